// Round 6
// baseline (10804.786 us; speedup 1.0000x reference)
//
#include <hip/hip_runtime.h>
#include <stdint.h>

#define B_ 256
#define S_ 512
#define H_ 256
#define G_ 1024
#define CHUNK 32
#define NCHUNK (S_ / CHUNK)

typedef __attribute__((ext_vector_type(8))) short bf16x8;
typedef __attribute__((ext_vector_type(4))) float f32x4;

__device__ __forceinline__ unsigned short f2bf(float f) {
    unsigned u = __builtin_bit_cast(unsigned, f);
    unsigned r = u + 0x7fffu + ((u >> 16) & 1u);
    return (unsigned short)(r >> 16);
}
__device__ __forceinline__ float bf2f(unsigned short v) {
    return __builtin_bit_cast(float, (unsigned)v << 16);
}
__device__ __forceinline__ float bfbits_lo(unsigned v) {
    return __builtin_bit_cast(float, (unsigned)(v << 16));
}
__device__ __forceinline__ float bfbits_hi(unsigned v) {
    return __builtin_bit_cast(float, v & 0xffff0000u);
}
__device__ __forceinline__ float sigmoidf_(float x) { return 1.f / (1.f + __expf(-x)); }
__device__ __forceinline__ float tanhf_(float x) { return 2.f / (1.f + __expf(-2.f * x)) - 1.f; }

// async global->LDS, 16B per lane; LDS dest wave-uniform base (+ lane*16 implicit)
__device__ __forceinline__ void gload_lds16(const void* g, void* s) {
    __builtin_amdgcn_global_load_lds((const __attribute__((address_space(1))) unsigned int*)g,
                                     (__attribute__((address_space(3))) unsigned int*)s, 16, 0, 0);
}

// ---------------- prep: weights -> fragment-major bf16 ----------------
// Wp[nt][kk][lane][i] = W[k][n], k = kk*32 + (lane>>4)*8 + i, n = nt*16 + (lane&15)
__global__ void prep_w(const float* __restrict__ W, unsigned short* __restrict__ Wp, int NT) {
    int tid = blockIdx.x * 256 + threadIdx.x;
    int total = NT * 8 * 64;
    if (tid >= total) return;
    int l = tid & 63, kk = (tid >> 6) & 7, nt = tid >> 9;
    int n = nt * 16 + (l & 15);
    int k0 = kk * 32 + (l >> 4) * 8;
    int N = NT * 16;
    unsigned short v[8];
#pragma unroll
    for (int i = 0; i < 8; i++) v[i] = f2bf(W[(size_t)(k0 + i) * N + n]);
    uint4 o;
    o.x = (unsigned)v[0] | ((unsigned)v[1] << 16);
    o.y = (unsigned)v[2] | ((unsigned)v[3] << 16);
    o.z = (unsigned)v[4] | ((unsigned)v[5] << 16);
    o.w = (unsigned)v[6] | ((unsigned)v[7] << 16);
    *(uint4*)(Wp + (size_t)tid * 8) = o;
}

__global__ void prep_decay(const float* __restrict__ x, float* __restrict__ dec, int n) {
    int i = blockIdx.x * 256 + threadIdx.x;
    if (i < n) dec[i] = 1.f / __logf(2.718281828459045f + x[(size_t)i * H_ + (H_ - 1)]);
}

// ---------------- xg GEMM body (unchanged) ----------------
template <bool SRCF32>
__device__ void gemm_body(const void* __restrict__ src, const unsigned short* __restrict__ Wp,
                          const float* __restrict__ bias, unsigned short* __restrict__ xgp,
                          int chunk, short* Albs) {
    const int tid = threadIdx.x;
    const int bx = blockIdx.x;
    const int by = blockIdx.y;
    const int r0 = bx * 128;
    const int t_loc = r0 >> 8;
    const int b0 = r0 & 255;
    const int sg = chunk * CHUNK + t_loc;
    {
        const int m = tid >> 1, kh = tid & 1;
        const size_t rowbase = ((size_t)(b0 + m) * S_ + sg) * H_ + kh * 128;
        if constexpr (SRCF32) {
            const float* p = (const float*)src + rowbase;
#pragma unroll
            for (int jo = 0; jo < 16; jo++) {
                int k = kh * 128 + jo * 8;
                float4 a = *(const float4*)(p + jo * 8);
                float4 b = *(const float4*)(p + jo * 8 + 4);
                int slot = ((m >> 4) * 8 + (k >> 5)) * 64 + ((m & 15) | (((k >> 3) & 3) << 4));
                uint4 o;
                o.x = (unsigned)f2bf(a.x) | ((unsigned)f2bf(a.y) << 16);
                o.y = (unsigned)f2bf(a.z) | ((unsigned)f2bf(a.w) << 16);
                o.z = (unsigned)f2bf(b.x) | ((unsigned)f2bf(b.y) << 16);
                o.w = (unsigned)f2bf(b.z) | ((unsigned)f2bf(b.w) << 16);
                *(uint4*)&Albs[slot * 8] = o;
            }
        } else {
            const unsigned short* p = (const unsigned short*)src + rowbase;
#pragma unroll
            for (int jo = 0; jo < 16; jo++) {
                int k = kh * 128 + jo * 8;
                uint4 o = *(const uint4*)(p + jo * 8);
                int slot = ((m >> 4) * 8 + (k >> 5)) * 64 + ((m & 15) | (((k >> 3) & 3) << 4));
                *(uint4*)&Albs[slot * 8] = o;
            }
        }
    }
    __syncthreads();
    const int w = tid >> 6, l = tid & 63;
    const int wm = w >> 1, wn = w & 1;
    const int col = l & 15;
    float bv[4];
#pragma unroll
    for (int q = 0; q < 4; q++) bv[q] = bias[(by * 8 + wn * 4 + q) * 16 + col];
    f32x4 acc[4][4];
#pragma unroll
    for (int mi = 0; mi < 4; mi++)
#pragma unroll
        for (int q = 0; q < 4; q++) {
            acc[mi][q][0] = bv[q]; acc[mi][q][1] = bv[q];
            acc[mi][q][2] = bv[q]; acc[mi][q][3] = bv[q];
        }
    const bf16x8* Wp8 = (const bf16x8*)Wp;
#pragma unroll
    for (int kk = 0; kk < 8; kk++) {
        bf16x8 af[4], bfr[4];
#pragma unroll
        for (int mi = 0; mi < 4; mi++)
            af[mi] = *(const bf16x8*)&Albs[(((wm * 4 + mi) * 8 + kk) * 64 + l) * 8];
#pragma unroll
        for (int q = 0; q < 4; q++)
            bfr[q] = Wp8[((size_t)(by * 8 + wn * 4 + q) * 8 + kk) * 64 + l];
#pragma unroll
        for (int mi = 0; mi < 4; mi++)
#pragma unroll
            for (int q = 0; q < 4; q++)
                acc[mi][q] = __builtin_amdgcn_mfma_f32_16x16x32_bf16(af[mi], bfr[q], acc[mi][q], 0, 0, 0);
    }
    const int rblk0 = r0 >> 4;
#pragma unroll
    for (int mi = 0; mi < 4; mi++) {
        int rowblk = rblk0 + wm * 4 + mi;
#pragma unroll
        for (int q = 0; q < 4; q++) {
            int qg = by * 8 + wn * 4 + q;
            uint2 o;
            o.x = (unsigned)f2bf(acc[mi][q][0]) | ((unsigned)f2bf(acc[mi][q][1]) << 16);
            o.y = (unsigned)f2bf(acc[mi][q][2]) | ((unsigned)f2bf(acc[mi][q][3]) << 16);
            *(uint2*)&xgp[(((size_t)rowblk * 64 + qg) * 64 + l) * 4] = o;
        }
    }
}

__global__ __launch_bounds__(256) void gemm_dual(const float* __restrict__ x,
                                                 const unsigned short* __restrict__ y0bf,
                                                 const unsigned short* __restrict__ Wp0,
                                                 const float* __restrict__ bias0,
                                                 const unsigned short* __restrict__ Wp1,
                                                 const float* __restrict__ bias1,
                                                 unsigned short* __restrict__ xgpA,
                                                 unsigned short* __restrict__ xgpB, int c0, int c1) {
    extern __shared__ short Albs[];  // 64 KB
    if (blockIdx.z == 0) {
        if (c0 < 0) return;
        gemm_body<true>(x, Wp0, bias0, xgpA, c0, Albs);
    } else {
        if (c1 < 0) return;
        gemm_body<false>(y0bf, Wp1, bias1, xgpB, c1, Albs);
    }
}

// ---------------- recurrent scan: LDS-RESIDENT Wh quarter, 4-WG groups ----------------
// Group = (layer,bblk) = gid; 4 WGs (qt=0..3) x 256 thr (4 waves). WG owns 64 output cols.
// Wave w owns col-tile ct=qt*4+w: 4 gate tiles in LDS (whb) + Wd tile in VGPRs.
// Per step: MFMA (LDS weights, loaded once/chunk) -> elementwise -> 4-way h/c exchange
// via parity-double-buffered payloads + epoch flags (agent-scope atomics, R4-proven).
template <bool ISL0>
__device__ void rec_run(const unsigned short* __restrict__ xgp, const bf16x8* __restrict__ Whp8,
                        const bf16x8* __restrict__ Wdp8, const float* __restrict__ bd,
                        const float* __restrict__ dec_in, void* __restrict__ yout,
                        float* __restrict__ dec_out, unsigned short* __restrict__ h_state,
                        float* __restrict__ c_state, unsigned* __restrict__ xch,
                        unsigned* __restrict__ flags, int chunk, int gid, int qt, int bblk,
                        char* smem) {
    short* whb = (short*)smem;                   // 128 KB: frag f=((w*4+q)*8+kk), 512 shorts each
    short* hb  = (short*)(smem + 131072);        // [16][256] bf16
    short* cb  = (short*)(smem + 139264);        // [16][256] bf16
    float* decs = (float*)(smem + 147456);       // [CHUNK][17]
    const int tid = threadIdx.x;                 // 0..255
    const int w = tid >> 6, l = tid & 63;
    const int lgrp = l >> 4, col = l & 15;
    const int b0 = bblk * 16;
    const int ct = qt * 4 + w;                   // col-tile 0..15
    const int n = ct * 16 + col;                 // output column
    const float bdv = bd[n];

#pragma unroll
    for (int i = 0; i < 2; i++) {  // stage decay
        int idx = tid + i * 256;
        int tt = idx & 31, row = idx >> 5;
        decs[tt * 17 + row] = dec_in[(size_t)(b0 + row) * S_ + chunk * CHUNK + tt];
    }
    // DMA Wh quarter into LDS once per chunk (32 KB per wave)
#pragma unroll
    for (int q = 0; q < 4; q++)
#pragma unroll
        for (int kk = 0; kk < 8; kk++)
            gload_lds16(Whp8 + ((size_t)(q * 16 + ct) * 8 + kk) * 64 + l,
                        whb + ((w * 4 + q) * 8 + kk) * 512);
    // Wd tile resident in registers
    bf16x8 wd[8];
#pragma unroll
    for (int kk = 0; kk < 8; kk++) wd[kk] = Wdp8[((size_t)ct * 8 + kk) * 64 + l];

    float creg[4];
    if (chunk == 0) {
#pragma unroll
        for (int r = 0; r < 4; r++) creg[r] = 0.f;
        for (int i = tid; i < 4096; i += 256) { hb[i] = 0; cb[i] = 0; }
    } else {
#pragma unroll
        for (int i = 0; i < 16; i++) {
            int idx = tid + i * 256;
            int row = idx >> 8, nn = idx & 255;
            int sw = nn ^ ((row & 7) << 3);
            hb[row * 256 + sw] = (short)h_state[(size_t)(b0 + row) * H_ + nn];
            cb[row * 256 + sw] = (short)f2bf(c_state[(size_t)(b0 + row) * H_ + nn]);
        }
#pragma unroll
        for (int r = 0; r < 4; r++)
            creg[r] = c_state[(size_t)(b0 + lgrp * 4 + r) * H_ + n];
    }
    const uint2* xg8 = (const uint2*)xgp;
    uint2 xc[4], xnx[4];
#pragma unroll
    for (int q = 0; q < 4; q++)
        xc[q] = xg8[((size_t)bblk * 64 + (q * 16 + ct)) * 64 + l];
    __builtin_amdgcn_s_waitcnt(0x0F70);  // vmcnt(0): DMA + staging loads done
    __builtin_amdgcn_sched_barrier(0);
    __syncthreads();

    unsigned* myflag = &flags[(gid * 4 + qt) * 32];

#pragma unroll 1
    for (int t = 0; t < CHUNK; ++t) {
        const int tg = chunk * CHUNK + t;
        if (t + 1 < CHUNK) {  // prefetch next step's xg
            int rb = (t + 1) * 16 + bblk;
#pragma unroll
            for (int q = 0; q < 4; q++)
                xnx[q] = xg8[((size_t)rb * 64 + (q * 16 + ct)) * 64 + l];
        }
        f32x4 csacc = {0.f, 0.f, 0.f, 0.f};
        f32x4 gacc[4];
#pragma unroll
        for (int q = 0; q < 4; q++) {
            uint2 v = xc[q];
            gacc[q][0] = bfbits_lo(v.x);
            gacc[q][1] = bfbits_hi(v.x);
            gacc[q][2] = bfbits_lo(v.y);
            gacc[q][3] = bfbits_hi(v.y);
        }
#pragma unroll
        for (int kk = 0; kk < 8; kk++) {
            const int ha = col * 256 + ((kk * 32 + lgrp * 8) ^ ((col & 7) << 3));
            bf16x8 hf = *(const bf16x8*)&hb[ha];
            bf16x8 cf = *(const bf16x8*)&cb[ha];
            csacc = __builtin_amdgcn_mfma_f32_16x16x32_bf16(cf, wd[kk], csacc, 0, 0, 0);
#pragma unroll
            for (int q = 0; q < 4; q++) {
                bf16x8 wf = *(const bf16x8*)&whb[(((w * 4 + q) * 8 + kk) * 64 + l) * 8];
                gacc[q] = __builtin_amdgcn_mfma_f32_16x16x32_bf16(hf, wf, gacc[q], 0, 0, 0);
            }
        }
        __syncthreads();  // b1: all hb/cb reads of this step done
        unsigned* xout = xch + ((size_t)((gid * 4 + qt) * 2 + (t & 1))) * 1024;
#pragma unroll
        for (int r = 0; r < 4; r++) {
            int row = lgrp * 4 + r;
            float cs = tanhf_(csacc[r] + bdv);
            float cadj = creg[r] - cs + cs * decs[t * 17 + row];
            float iv = sigmoidf_(gacc[0][r]);
            float fv = sigmoidf_(gacc[1][r]);
            float ov = sigmoidf_(gacc[2][r]);
            float cd = tanhf_(gacc[3][r]);
            float cn = fv * cadj + iv * cd;
            float hn = ov * tanhf_(cn);
            creg[r] = cn;
            int sw = n ^ ((row & 7) << 3);
            unsigned hnb = f2bf(hn), cnb = f2bf(cn);
            hb[row * 256 + sw] = (short)hnb;
            cb[row * 256 + sw] = (short)cnb;
            if (t + 1 < CHUNK)
                __hip_atomic_store(&xout[row * 64 + w * 16 + col], hnb | (cnb << 16),
                                   __ATOMIC_RELAXED, __HIP_MEMORY_SCOPE_AGENT);
            size_t yi = ((size_t)(b0 + row) * S_ + tg) * H_ + n;
            if constexpr (ISL0) {
                ((unsigned short*)yout)[yi] = (unsigned short)hnb;
                if (ct == 15 && col == 15)
                    dec_out[(size_t)(b0 + row) * S_ + tg] = 1.f / __logf(2.718281828459045f + hn);
            } else {
                ((float*)yout)[yi] = hn;
            }
            if (t == CHUNK - 1) {
                h_state[(size_t)(b0 + row) * H_ + n] = (unsigned short)hnb;
                c_state[(size_t)(b0 + row) * H_ + n] = cn;
            }
        }
        if (t + 1 < CHUNK) {
            const unsigned ep = (unsigned)(chunk * CHUNK + t + 1);
            __threadfence();     // payload agent-visible before flag
            __syncthreads();     // b2: all threads stored+fenced
            if (tid == 0)
                __hip_atomic_store(myflag, ep, __ATOMIC_RELEASE, __HIP_MEMORY_SCOPE_AGENT);
            if (l == 0 && w > 0) {  // lane0 of waves 1..3 each spin one partner
                unsigned* pf = &flags[(gid * 4 + ((qt + w) & 3)) * 32];
                int spins = 0;
                while (__hip_atomic_load(pf, __ATOMIC_ACQUIRE, __HIP_MEMORY_SCOPE_AGENT) < ep) {
                    __builtin_amdgcn_s_sleep(1);
                    if (++spins > 100000000) break;
                }
            }
            __syncthreads();     // b3: partners published
#pragma unroll
            for (int j = 0; j < 3; j++) {
                int pp = (qt + 1 + j) & 3;
                unsigned* xin = xch + ((size_t)((gid * 4 + pp) * 2 + (t & 1))) * 1024;
#pragma unroll
                for (int i = 0; i < 4; i++) {
                    int idx = tid + i * 256;
                    unsigned v = __hip_atomic_load(&xin[idx], __ATOMIC_RELAXED,
                                                   __HIP_MEMORY_SCOPE_AGENT);
                    int row = idx >> 6, lc = idx & 63;
                    int n2 = pp * 64 + lc;
                    int sw2 = n2 ^ ((row & 7) << 3);
                    hb[row * 256 + sw2] = (short)(v & 0xffffu);
                    cb[row * 256 + sw2] = (short)(v >> 16);
                }
            }
            __syncthreads();     // b4: hb/cb complete for next step
        }
#pragma unroll
        for (int q = 0; q < 4; q++) xc[q] = xnx[q];
    }
}

// 128 WGs: b = qt*32 + gid; gid = layer*16 + bblk. Quarters of a group share b%8 (same XCD).
__global__ __launch_bounds__(256, 1) void rec_fused(
    const unsigned short* __restrict__ xgpA, const unsigned short* __restrict__ Whp0,
    const unsigned short* __restrict__ Wdp0, const float* __restrict__ bd0,
    const float* __restrict__ dec0, unsigned short* __restrict__ y0bf,
    float* __restrict__ dec1, unsigned short* __restrict__ hs0, float* __restrict__ cs0,
    const unsigned short* __restrict__ xgpB, const unsigned short* __restrict__ Whp1,
    const unsigned short* __restrict__ Wdp1, const float* __restrict__ bd1,
    float* __restrict__ y1, unsigned short* __restrict__ hs1, float* __restrict__ cs1,
    unsigned* __restrict__ xch, unsigned* __restrict__ flags, int c0, int c1) {
    extern __shared__ char smem[];
    int qt = blockIdx.x >> 5, gid = blockIdx.x & 31;
    int layer = gid >> 4, bblk = gid & 15;
    if (layer == 0) {
        if (c0 < 0) return;
        rec_run<true>(xgpA, (const bf16x8*)Whp0, (const bf16x8*)Wdp0, bd0, dec0, y0bf, dec1,
                      hs0, cs0, xch, flags, c0, gid, qt, bblk, smem);
    } else {
        if (c1 < 0) return;
        rec_run<false>(xgpB, (const bf16x8*)Whp1, (const bf16x8*)Wdp1, bd1, dec1, y1, nullptr,
                       hs1, cs1, xch, flags, c1, gid, qt, bblk, smem);
    }
}

__global__ void copy_tail(const unsigned short* __restrict__ h0, const float* __restrict__ c0,
                          const unsigned short* __restrict__ h1, const float* __restrict__ c1,
                          float* __restrict__ out) {
    int i = blockIdx.x * 256 + threadIdx.x;
    if (i >= 4 * 65536) return;
    int which = i >> 16, j = i & 65535;
    float v = which == 0 ? bf2f(h0[j]) : which == 1 ? c0[j] : which == 2 ? bf2f(h1[j]) : c1[j];
    out[i] = v;
}

extern "C" void kernel_launch(void* const* d_in, const int* in_sizes, int n_in, void* d_out,
                              int out_size, void* d_ws, size_t ws_size, hipStream_t stream) {
    (void)in_sizes; (void)n_in; (void)out_size; (void)ws_size;
    const float* x   = (const float*)d_in[0];
    const float* Wx0 = (const float*)d_in[1];
    const float* Wh0 = (const float*)d_in[2];
    const float* b0  = (const float*)d_in[3];
    const float* Wd0 = (const float*)d_in[4];
    const float* bd0 = (const float*)d_in[5];
    const float* Wx1 = (const float*)d_in[6];
    const float* Wh1 = (const float*)d_in[7];
    const float* b1  = (const float*)d_in[8];
    const float* Wd1 = (const float*)d_in[9];
    const float* bd1 = (const float*)d_in[10];

    char* ws = (char*)d_ws;
    size_t off = 0;
    auto take = [&](size_t bytes) { void* p = ws + off; off += (bytes + 255) & ~(size_t)255; return p; };
    unsigned short* wxp0 = (unsigned short*)take(524288);
    unsigned short* whp0 = (unsigned short*)take(524288);
    unsigned short* wdp0 = (unsigned short*)take(131072);
    unsigned short* wxp1 = (unsigned short*)take(524288);
    unsigned short* whp1 = (unsigned short*)take(524288);
    unsigned short* wdp1 = (unsigned short*)take(131072);
    float* dec0 = (float*)take(524288);
    float* dec1 = (float*)take(524288);
    unsigned short* hs0 = (unsigned short*)take(131072);
    float* cs0 = (float*)take(262144);
    unsigned short* hs1 = (unsigned short*)take(131072);
    float* cs1 = (float*)take(262144);
    unsigned short* y0bf = (unsigned short*)take(67108864);
    unsigned short* xgpA = (unsigned short*)take(16777216);
    unsigned short* xgpB = (unsigned short*)take(16777216);
    unsigned* xch   = (unsigned*)take(32 * 4 * 2 * 1024 * 4);  // 1 MB exchange payloads
    unsigned* flags = (unsigned*)take(32 * 4 * 32 * 4);        // 16 KB epoch flags

    hipMemsetAsync(flags, 0, 32 * 4 * 32 * 4, stream);

    const size_t smem_rec = 131072 + 8192 + 8192 + 2176;  // 149632 B
    hipFuncSetAttribute(reinterpret_cast<const void*>(&rec_fused),
                        hipFuncAttributeMaxDynamicSharedMemorySize, (int)smem_rec);
    hipFuncSetAttribute(reinterpret_cast<const void*>(&gemm_dual),
                        hipFuncAttributeMaxDynamicSharedMemorySize, 65536);

    prep_w<<<128, 256, 0, stream>>>(Wx0, wxp0, 64);
    prep_w<<<128, 256, 0, stream>>>(Wh0, whp0, 64);
    prep_w<<<32, 256, 0, stream>>>(Wd0, wdp0, 16);
    prep_w<<<128, 256, 0, stream>>>(Wx1, wxp1, 64);
    prep_w<<<128, 256, 0, stream>>>(Wh1, whp1, 64);
    prep_w<<<32, 256, 0, stream>>>(Wd1, wdp1, 16);
    prep_decay<<<512, 256, 0, stream>>>(x, dec0, B_ * S_);

    float* y1 = (float*)d_out;
    for (int s = 0; s <= NCHUNK; ++s) {
        int c0 = (s < NCHUNK) ? s : -1;
        int c1 = (s >= 1) ? s - 1 : -1;
        gemm_dual<<<dim3(64, 8, 2), 256, 65536, stream>>>(x, y0bf, wxp0, b0, wxp1, b1,
                                                          xgpA, xgpB, c0, c1);
        rec_fused<<<128, 256, smem_rec, stream>>>(xgpA, whp0, wdp0, bd0, dec0, y0bf, dec1,
                                                  hs0, cs0, xgpB, whp1, wdp1, bd1, y1,
                                                  hs1, cs1, xch, flags, c0, c1);
    }
    copy_tail<<<1024, 256, 0, stream>>>(hs0, cs0, hs1, cs1, y1 + (size_t)B_ * S_ * H_);
}